// Round 5
// baseline (531.046 us; speedup 1.0000x reference)
//
#include <hip/hip_runtime.h>

// ---- problem dims ----
#define IN_DIM 8193
#define OUT_DIM 4097
#define NB 1024
// padded dims
#define MP1 8320
#define KP1 8320   // K padded to mult of 128 for clean split-K over BK=64
#define MP2 4224
#define KP2 4160

typedef __attribute__((ext_vector_type(8))) short short8;
typedef __attribute__((ext_vector_type(4))) float f32x4;

__device__ __forceinline__ unsigned short f2bf(float f) {
  unsigned int u = __float_as_uint(f);
  u = (u + 0x7fffu + ((u >> 16) & 1u)) >> 16;  // RNE
  return (unsigned short)u;
}

// ---- pad + f32->bf16 convert (row-major -> row-major padded) ----
__global__ __launch_bounds__(256) void cvt_pad_kernel(
    const float* __restrict__ src, unsigned short* __restrict__ dst,
    int sR, int sC, int dR, int dC) {
  int gid = blockIdx.x * 256 + threadIdx.x;
  int i4 = gid * 4;
  if (i4 >= dR * dC) return;
  int r = i4 / dC;
  int c = i4 - r * dC;   // dC % 4 == 0 so never crosses a row
  unsigned short o[4];
#pragma unroll
  for (int j = 0; j < 4; ++j) {
    int cc = c + j;
    float v = (r < sR && cc < sC) ? src[(size_t)r * sC + cc] : 0.f;
    o[j] = f2bf(v);
  }
  unsigned int lo = (unsigned)o[0] | ((unsigned)o[1] << 16);
  unsigned int hi = (unsigned)o[2] | ((unsigned)o[3] << 16);
  *reinterpret_cast<uint2*>(dst + i4) = make_uint2(lo, hi);
}

// ---- transpose + convert: src (K x N) f32 -> dst (N x Kp) bf16, zero pad ----
__global__ __launch_bounds__(256) void transpose_cvt_kernel(
    const float* __restrict__ src, unsigned short* __restrict__ dst,
    int K, int N, int Kp) {
  __shared__ float tl[32][33];
  const int ntk = Kp >> 5;
  int bx = blockIdx.x % ntk;
  int by = blockIdx.x / ntk;
  int k0 = bx * 32, n0 = by * 32;
  int tx = threadIdx.x & 31, ty = threadIdx.x >> 5;
#pragma unroll
  for (int i = 0; i < 4; ++i) {
    int k = k0 + ty + i * 8;
    tl[ty + i * 8][tx] = (k < K) ? src[(size_t)k * N + n0 + tx] : 0.f;
  }
  __syncthreads();
#pragma unroll
  for (int i = 0; i < 4; ++i) {
    int n = n0 + ty + i * 8;
    dst[(size_t)n * Kp + k0 + tx] = f2bf(tl[tx][ty + i * 8]);
  }
}

// ---- Ring-3 pipelined GEMM: Cpart(sp) = Ab(:,ksplit) * Bt(:,ksplit)^T ----
// Tile 128x256, BK=64, 8 waves (2Mx4N, per-wave 64x64), LDS ring of 3 slots
// (slot = A 16KB + B 32KB = 48KB; 144KB total). One phase per K-tile:
//   vmcnt(6); barrier; STAGE(tile t+2 -> slot (t+2)%3); 16 ds_read; 32 MFMA.
// Invariants: slot (t+2)%3 holds tile t-1 (dead at this phase's barrier);
// tile t's 6 loads issued at phase t-2 -> vmcnt(6) exactly lands them.
// XOR granule swizzle (g ^= row&7) on global source + ds_read (0-conflict).
__global__ __launch_bounds__(512) void gemm_ring(
    const unsigned short* __restrict__ Ab,
    const unsigned short* __restrict__ Bt,
    float* __restrict__ C,
    int Kp, int Mout, int nbm, int nsplit) {
  extern __shared__ unsigned short lds[];   // 3 * 24576 shorts
  const int tid = threadIdx.x;
  const int wid = tid >> 6;
  const int lane = tid & 63;
  const int bps = nbm * 4;                  // nbn = 4 (N=1024, BN=256)
  const int sp = blockIdx.x / bps;
  const int i = blockIdx.x - sp * bps;
  // XCD grouping: the 4 bn-blocks of one bm land on one XCD (share A panel)
  const int fullm = nbm & ~7;
  const int F = fullm * 4;
  int bm, bn;
  if (i < F) {
    const int g = i & 7;
    const int r = i >> 3;
    bm = g * (fullm >> 3) + (r >> 2);
    bn = r & 3;
  } else {
    const int j = i - F;
    bm = fullm + (j >> 2);
    bn = j & 3;
  }
  const int m0 = bm << 7;
  const int n0 = bn << 8;
  const int wm = (wid >> 2) << 6;    // 0 / 64
  const int wn = (wid & 3) << 6;     // 0 / 64 / 128 / 192

  // K-tile range for this split
  const int nk = Kp >> 6;
  const int q = nk / nsplit, rr = nk - q * nsplit;
  const int kt0 = sp * q + (sp < rr ? sp : rr);
  const int T = q + (sp < rr ? 1 : 0);
  float* Cp = C + (size_t)sp * Mout * NB;

  // per-lane slot-relative LDS offsets (shorts)
  int aoff[4][2], boff[4][2];
#pragma unroll
  for (int mf = 0; mf < 4; ++mf)
#pragma unroll
    for (int kk = 0; kk < 2; ++kk) {
      const int row = wm + mf * 16 + (lane & 15);
      const int g = (kk * 4 + (lane >> 4)) ^ (row & 7);
      aoff[mf][kk] = row * 64 + g * 8;
    }
#pragma unroll
  for (int nf = 0; nf < 4; ++nf)
#pragma unroll
    for (int kk = 0; kk < 2; ++kk) {
      const int row = wn + nf * 16 + (lane & 15);
      const int g = (kk * 4 + (lane >> 4)) ^ (row & 7);
      boff[nf][kk] = 8192 + row * 64 + g * 8;
    }

  f32x4 acc[4][4] = {};

#define STAGE(KT, SLOT)                                                        \
  do {                                                                         \
    const int k0_ = (KT) << 6;                                                 \
    unsigned short* base_ = lds + (SLOT) * 24576;                              \
    _Pragma("unroll")                                                          \
    for (int L = 0; L < 2; ++L) {                                              \
      const int s_ = L * 512 + tid;                                            \
      const int row_ = s_ >> 3;                                                \
      const int gl_ = (s_ & 7) ^ (row_ & 7);                                   \
      const unsigned short* ga_ = Ab + (size_t)(m0 + row_) * Kp + (k0_ + gl_ * 8); \
      unsigned short* la_ = base_ + (size_t)(L * 512 + wid * 64) * 8;          \
      __builtin_amdgcn_global_load_lds(                                        \
          (const __attribute__((address_space(1))) void*)ga_,                  \
          (__attribute__((address_space(3))) void*)la_, 16, 0, 0);             \
    }                                                                          \
    _Pragma("unroll")                                                          \
    for (int L = 0; L < 4; ++L) {                                              \
      const int s_ = L * 512 + tid;                                            \
      const int row_ = s_ >> 3;                                                \
      const int gl_ = (s_ & 7) ^ (row_ & 7);                                   \
      const unsigned short* gb_ = Bt + (size_t)(n0 + row_) * Kp + (k0_ + gl_ * 8); \
      unsigned short* lb_ = base_ + 8192 + (size_t)(L * 512 + wid * 64) * 8;   \
      __builtin_amdgcn_global_load_lds(                                        \
          (const __attribute__((address_space(1))) void*)gb_,                  \
          (__attribute__((address_space(3))) void*)lb_, 16, 0, 0);             \
    }                                                                          \
  } while (0)

  // prologue: tiles kt0 -> slot0, kt0+1 -> slot1 (T >= 16 always here)
  STAGE(kt0, 0);
  STAGE(kt0 + 1, 1);

  int sa = 0, sb = 1, sc = 2;
  for (int t = 0; t < T; ++t) {
    // tile t's loads (issued at phase t-2 / prologue) are the oldest;
    // at most phase t-1's 6 loads may remain in flight.
    asm volatile("s_waitcnt vmcnt(6)" ::: "memory");
    __builtin_amdgcn_s_barrier();
    __builtin_amdgcn_sched_barrier(0);
    // prefetch tile t+2 into the slot that held tile t-1 (clamped at tail;
    // clamp re-stages a valid tile so the vmcnt count stays uniform)
    const int ktp = kt0 + ((t + 2 < T) ? (t + 2) : (T - 1));
    STAGE(ktp, sc);
    const unsigned short* base = lds + sa * 24576;
    short8 af[4][2], bfr[4][2];
#pragma unroll
    for (int mf = 0; mf < 4; ++mf)
#pragma unroll
      for (int kk = 0; kk < 2; ++kk)
        af[mf][kk] = *reinterpret_cast<const short8*>(base + aoff[mf][kk]);
#pragma unroll
    for (int nf = 0; nf < 4; ++nf)
#pragma unroll
      for (int kk = 0; kk < 2; ++kk)
        bfr[nf][kk] = *reinterpret_cast<const short8*>(base + boff[nf][kk]);
    __builtin_amdgcn_s_setprio(1);
#pragma unroll
    for (int kk = 0; kk < 2; ++kk)
#pragma unroll
      for (int mf = 0; mf < 4; ++mf)
#pragma unroll
        for (int nf = 0; nf < 4; ++nf)
          asm volatile("v_mfma_f32_16x16x32_bf16 %0, %1, %2, %0"
                       : "+v"(acc[mf][nf])
                       : "v"(af[mf][kk]), "v"(bfr[nf][kk]));
    __builtin_amdgcn_s_setprio(0);
    const int tmp = sa; sa = sb; sb = sc; sc = tmp;
  }
#undef STAGE

  // epilogue: C/D layout col=lane&15, row=(lane>>4)*4+reg  [m89-verified]
#pragma unroll
  for (int mf = 0; mf < 4; ++mf) {
    const int rbase = m0 + wm + mf * 16 + (lane >> 4) * 4;
#pragma unroll
    for (int nf = 0; nf < 4; ++nf) {
      const int col = n0 + wn + nf * 16 + (lane & 15);
#pragma unroll
      for (int r = 0; r < 4; ++r) {
        const int row = rbase + r;
        if (row < Mout) Cp[(size_t)row * NB + col] = acc[mf][nf][r];
      }
    }
  }
}

// ---- conv: z = za+zb (8193 x 1024) f32 -> tT (1024 x KP2) bf16 ----
__global__ __launch_bounds__(256) void conv_tT_kernel(
    const float* __restrict__ za, const float* __restrict__ zb,
    const float* __restrict__ w, const float* __restrict__ bias,
    unsigned short* __restrict__ tT) {
  const int gid = blockIdx.x * 256 + threadIdx.x;
  const int n = gid & 1023;
  const int rg = gid >> 10;  // 0..519
  const int r0 = rg << 3;
  const size_t homoff = (size_t)8192 * 1024 + n;
  const float hom = za[homoff] + zb[homoff];
  unsigned short o[8];
  if (r0 >= 4096) {
#pragma unroll
    for (int j = 0; j < 8; ++j) o[j] = f2bf((r0 + j == 4096) ? hom : 0.f);
  } else {
    const int co = r0 >> 8;
    const int uo = (r0 >> 4) & 15;
    const int vo0 = r0 & 15;  // 0 or 8
    float acc[8];
    const float bb = bias[co];
#pragma unroll
    for (int j = 0; j < 8; ++j) acc[j] = bb * hom;
    for (int ci = 0; ci < 8; ++ci) {
#pragma unroll
      for (int kh = 0; kh < 3; ++kh) {
        const int u = uo * 2 + kh;
        if (u >= 32) continue;
        const size_t zoff = (size_t)(ci * 1024 + u * 32) * 1024 + n;
#pragma unroll
        for (int kw = 0; kw < 3; ++kw) {
          const float wv = w[((co * 8 + ci) * 3 + kh) * 3 + kw];
#pragma unroll
          for (int j = 0; j < 8; ++j) {
            const int v = (vo0 + j) * 2 + kw;
            if (v < 32) {
              const size_t e = zoff + (size_t)v * 1024;
              acc[j] += wv * (za[e] + zb[e]);
            }
          }
        }
      }
    }
#pragma unroll
    for (int j = 0; j < 8; ++j) o[j] = f2bf(acc[j]);
  }
  uint4 pv;
  pv.x = (unsigned)o[0] | ((unsigned)o[1] << 16);
  pv.y = (unsigned)o[2] | ((unsigned)o[3] << 16);
  pv.z = (unsigned)o[4] | ((unsigned)o[5] << 16);
  pv.w = (unsigned)o[6] | ((unsigned)o[7] << 16);
  *reinterpret_cast<uint4*>(tT + (size_t)n * KP2 + r0) = pv;
}

// ---- final sum of 4 split-K partials -> d_out ----
__global__ __launch_bounds__(256) void sum4_kernel(
    const float* __restrict__ p, float* __restrict__ out, int n4) {
  const int i = blockIdx.x * 256 + threadIdx.x;
  if (i >= n4) return;
  const size_t stride4 = (size_t)OUT_DIM * NB / 4;
  const float4* p4 = (const float4*)p;
  float4 a = p4[i];
  float4 b = p4[i + stride4];
  float4 c = p4[i + 2 * stride4];
  float4 d = p4[i + 3 * stride4];
  float4 r;
  r.x = (a.x + b.x) + (c.x + d.x);
  r.y = (a.y + b.y) + (c.y + d.y);
  r.z = (a.z + b.z) + (c.z + d.z);
  r.w = (a.w + b.w) + (c.w + d.w);
  reinterpret_cast<float4*>(out)[i] = r;
}

extern "C" void kernel_launch(void* const* d_in, const int* in_sizes, int n_in,
                              void* d_out, int out_size, void* d_ws, size_t ws_size,
                              hipStream_t stream) {
  const float* w    = (const float*)d_in[0];  // (16,8,3,3)
  const float* bias = (const float*)d_in[1];  // (16,)
  const float* A    = (const float*)d_in[2];  // (4097,4097)
  const float* Ainv = (const float*)d_in[3];  // (8193,8193)
  const float* x    = (const float*)d_in[4];  // (8193,1024)
  float* out = (float*)d_out;                 // (4097,1024)

  // Workspace (231.1 MB <= round-2-proven 231.5 MB):
  //   Ainv_b 138.45 | xT_b 17.04 | z2 67.12 | tT_b 8.52
  //   A2_b aliases z2 (after conv); outp (4x16.8MB) aliases Ainv_b (after GEMM1)
  char* ws = (char*)d_ws;
  unsigned short* Ainv_b = (unsigned short*)(ws);
  unsigned short* xT_b   = (unsigned short*)(ws + (size_t)MP1 * KP1 * 2);
  float*          z2     = (float*)(ws + (size_t)MP1 * KP1 * 2 + (size_t)NB * KP1 * 2);
  unsigned short* tT_b   = (unsigned short*)(ws + (size_t)MP1 * KP1 * 2 + (size_t)NB * KP1 * 2
                                             + (size_t)2 * IN_DIM * NB * 4);
  unsigned short* A2_b   = (unsigned short*)z2;
  float*          outp   = (float*)Ainv_b;
  (void)ws_size; (void)in_sizes; (void)n_in; (void)out_size;

  hipFuncSetAttribute((const void*)gemm_ring,
                      hipFuncAttributeMaxDynamicSharedMemorySize, 147456);

  // 1) Ainv -> padded bf16 (MP1 x KP1)
  cvt_pad_kernel<<<(MP1 * KP1 / 4 + 255) / 256, 256, 0, stream>>>(
      Ainv, Ainv_b, IN_DIM, IN_DIM, MP1, KP1);
  // 2) x -> x^T padded bf16 (NB x KP1)
  transpose_cvt_kernel<<<(KP1 / 32) * (NB / 32), 256, 0, stream>>>(
      x, xT_b, IN_DIM, NB, KP1);
  // 3) z{a,b} = Ainv @ x  (ring-3 GEMM, split-K=2 -> 520 blocks)
  gemm_ring<<<2 * 65 * 4, 512, 147456, stream>>>(
      Ainv_b, xT_b, z2, KP1, IN_DIM, 65, 2);
  // 4) t^T = conv(za+zb)
  conv_tT_kernel<<<(520 * 1024) / 256, 256, 0, stream>>>(
      z2, z2 + (size_t)IN_DIM * NB, w, bias, tT_b);
  // 5) A -> padded bf16 (MP2 x KP2)  [z2 dead; alias]
  cvt_pad_kernel<<<(MP2 * KP2 / 4 + 255) / 256, 256, 0, stream>>>(
      A, A2_b, OUT_DIM, OUT_DIM, MP2, KP2);
  // 6) outp[0..3] = A @ t  (ring-3 GEMM, split-K=4 -> 528 blocks)
  gemm_ring<<<4 * 33 * 4, 512, 147456, stream>>>(
      A2_b, tT_b, outp, KP2, OUT_DIM, 33, 4);
  // 7) out = sum of partials
  const int n4 = OUT_DIM * NB / 4;
  sum4_kernel<<<(n4 + 255) / 256, 256, 0, stream>>>(outp, out, n4);
}